// Round 6
// baseline (653.327 us; speedup 1.0000x reference)
//
#include <hip/hip_runtime.h>
#include <hip/hip_bf16.h>
#include <cstdint>
#include <cstddef>

// B=2, L=2048, D=1024, F=4096, E=8, K=2
#define B_ 2
#define L_ 2048
#define D_ 1024
#define F_ 4096
#define E_ 8
#define NTOK 4096
#define MAXROWS 9216   // sum over experts of pad128(n_e) <= 8192 + 8*127
#define MAXMT 72       // MAXROWS / 128

typedef __hip_bfloat16 bf16;
typedef __attribute__((ext_vector_type(8))) short short8;
typedef __attribute__((ext_vector_type(4))) float floatx4;

typedef const __attribute__((address_space(1))) uint32_t* gptr_t;
typedef __attribute__((address_space(3))) uint32_t* lptr_t;

__device__ __forceinline__ void async_load16(const bf16* gp, bf16* lp) {
    __builtin_amdgcn_global_load_lds((gptr_t)(const void*)gp, (lptr_t)(void*)lp, 16, 0, 0);
}

__device__ __forceinline__ uint16_t bfbits(bf16 h) {
    union { bf16 b; uint16_t u; } v; v.b = h; return v.u;
}
__device__ __forceinline__ uint32_t pack2(float a, float b) {
    return (uint32_t)bfbits(__float2bfloat16(a)) | ((uint32_t)bfbits(__float2bfloat16(b)) << 16);
}

// tanh-form GELU: x * sigmoid(2*sqrt(2/pi)*(x + 0.044715 x^3)); max |err| vs exact ~3e-4
__device__ __forceinline__ float fast_gelu(float x) {
    float x2 = x * x;
    float z = x * fmaf(0.1029432f, x2, 2.3022081f);   // 2*log2(e)*0.7978845608*(1, 0.044715)
    z = fminf(z, 120.f);                               // avoid inf/inf
    float u = __builtin_amdgcn_exp2f(z);
    return x * u * __builtin_amdgcn_rcpf(1.f + u);
}

// ---------------- gating: 256 blocks x 256 thr, 16 tokens/block (4/wave) ----------------
__global__ __launch_bounds__(256) void gate_kernel(
    const float* __restrict__ x, const float* __restrict__ Wg,
    const float* __restrict__ bg, float* __restrict__ psum_pad,
    uint32_t* __restrict__ top_ids, float* __restrict__ top_w)
{
    __shared__ float psum_l[E_];
    int t = threadIdx.x;
    if (t < E_) psum_l[t] = 0.f;
    __syncthreads();

    int wave = t >> 6, lane = t & 63;
    for (int j = 0; j < 4; ++j) {
        int token = blockIdx.x * 16 + wave * 4 + j;
        const float* xr = x + (size_t)token * D_;

        float acc[E_];
#pragma unroll
        for (int e = 0; e < E_; ++e) acc[e] = 0.f;
#pragma unroll
        for (int i = 0; i < 4; ++i) {
            int d = lane * 4 + 256 * i;
            float4 xv = *(const float4*)(xr + d);
            const float* xs = &xv.x;
#pragma unroll
            for (int jj = 0; jj < 4; ++jj) {
                const float4* wr4 = (const float4*)(Wg + (size_t)(d + jj) * E_);
                float4 wa = wr4[0], wb = wr4[1];
                float xvj = xs[jj];
                acc[0] += xvj * wa.x;  acc[1] += xvj * wa.y;
                acc[2] += xvj * wa.z;  acc[3] += xvj * wa.w;
                acc[4] += xvj * wb.x;  acc[5] += xvj * wb.y;
                acc[6] += xvj * wb.z;  acc[7] += xvj * wb.w;
            }
        }
#pragma unroll
        for (int off = 32; off >= 1; off >>= 1) {
#pragma unroll
            for (int e = 0; e < E_; ++e) acc[e] += __shfl_xor(acc[e], off, 64);
        }
        if (lane == 0) {
            float s[E_];
#pragma unroll
            for (int e = 0; e < E_; ++e) s[e] = acc[e] + bg[e];
            int i0 = 0;
#pragma unroll
            for (int e = 1; e < E_; ++e) if (s[e] > s[i0]) i0 = e;
            int i1 = -1;
#pragma unroll
            for (int e = 0; e < E_; ++e) {
                if (e == i0) continue;
                if (i1 < 0 || s[e] > s[i1]) i1 = e;
            }
            float e1 = expf(s[i1] - s[i0]);
            float w0 = 1.f / (1.f + e1);
            float w1 = e1 * w0;
            top_ids[token] = (uint32_t)i0 | ((uint32_t)i1 << 8);
            top_w[token]        = w0;
            top_w[NTOK + token] = w1;

            float mx = s[i0], p[E_], sum = 0.f;
#pragma unroll
            for (int e = 0; e < E_; ++e) { p[e] = expf(s[e] - mx); sum += p[e]; }
            float inv = 1.f / sum;
#pragma unroll
            for (int e = 0; e < E_; ++e) atomicAdd(&psum_l[e], p[e] * inv);
        }
    }
    __syncthreads();
    if (t < E_) atomicAdd(&psum_pad[t * 32], psum_l[t]);
}

// ---------------- dispatch: compact + finalize + gather fused (no grid sync) ----------------
// All 256 blocks redundantly scan top_ids (16 KB, L2-resident) and reproduce the exact
// deterministic per-expert positions via per-chunk ballots (identical to the old
// compact_kernel ordering). Each block copies only rows it owns (row%256==bid; each
// residue class has exactly 36 rows in [0,9216) so the 64-slot queue cannot overflow),
// and writes tok_row/w_row for those rows. Block 0 emits cnt/off/mt_map/mt_hdr/loss.
__global__ __launch_bounds__(256) void dispatch_kernel(
    const float* __restrict__ x, const uint32_t* __restrict__ top_ids,
    const float* __restrict__ top_w, const float* __restrict__ psum_pad,
    int* __restrict__ cnt, int* __restrict__ off_g,
    int* __restrict__ mt_map, int* __restrict__ mt_hdr,
    int* __restrict__ tok_row, float* __restrict__ w_row,
    bf16* __restrict__ Xg, float* __restrict__ loss_out)
{
    __shared__ int cnt_l[E_];
    __shared__ int off_l[E_];
    __shared__ int base_l[E_];
    __shared__ int wcnt[E_][4];
    __shared__ int qrow[64];
    __shared__ int qtok[64];
    __shared__ float qw[64];
    __shared__ int qn;

    int t = threadIdx.x, wave = t >> 6, lane = t & 63;
    int bid = blockIdx.x;
    if (t < E_) cnt_l[t] = 0;
    if (t == 0) qn = 0;
    __syncthreads();

    // ---- pass 1: per-expert counts ----
    uint32_t myids[16];
    int lc[E_];
#pragma unroll
    for (int e = 0; e < E_; ++e) lc[e] = 0;
#pragma unroll
    for (int c = 0; c < 16; ++c) {
        int token = c * 256 + t;
        uint32_t ids = top_ids[token];
        myids[c] = ids;
        int e0 = (int)(ids & 255u), e1 = (int)((ids >> 8) & 255u);
#pragma unroll
        for (int e = 0; e < E_; ++e) lc[e] += (e0 == e) + (e1 == e);
    }
#pragma unroll
    for (int e = 0; e < E_; ++e) {
        int v = lc[e];
#pragma unroll
        for (int off = 32; off >= 1; off >>= 1) v += __shfl_xor(v, off, 64);
        if (lane == 0) atomicAdd(&cnt_l[e], v);
    }
    __syncthreads();

    if (t == 0) {
        int o = 0;
#pragma unroll
        for (int e = 0; e < E_; ++e) { off_l[e] = o; o += (cnt_l[e] + 127) & ~127; }
    }
    if (t < E_) base_l[t] = 0;
    __syncthreads();

    if (bid == 0 && t == 0) {
        int g = 0;
        for (int e = 0; e < E_; ++e) {
            cnt[e] = cnt_l[e]; off_g[e] = off_l[e];
            int mtn = (cnt_l[e] + 127) >> 7;
            for (int m = 0; m < mtn; ++m) mt_map[g++] = (e << 8) | m;
        }
        mt_hdr[0] = g;
        mt_hdr[1] = (g + 7) >> 3;
        float Ls = 0.f;
        for (int e = 0; e < E_; ++e) Ls += (float)cnt_l[e] * psum_pad[e * 32];
        loss_out[0] = (float)E_ * Ls / ((float)NTOK * (float)NTOK);
    }

    // ---- pass 2: deterministic positions via ballots; enqueue owned rows ----
#pragma unroll
    for (int c = 0; c < 16; ++c) {
        uint32_t ids = myids[c];
        int e0 = (int)(ids & 255u), e1 = (int)((ids >> 8) & 255u);
        int lp0 = 0, lp1 = 0;
#pragma unroll
        for (int e = 0; e < E_; ++e) {
            bool m = (e0 == e) || (e1 == e);
            unsigned long long mk = __ballot(m);
            if (lane == 0) wcnt[e][wave] = (int)__popcll(mk);
            int lp = (int)__popcll(mk & ((1ull << lane) - 1ull));
            if (e0 == e) lp0 = lp;
            if (e1 == e) lp1 = lp;
        }
        __syncthreads();
        int woff0 = 0, woff1 = 0;
#pragma unroll
        for (int w2 = 0; w2 < 4; ++w2) {
            if (w2 < wave) { woff0 += wcnt[e0][w2]; woff1 += wcnt[e1][w2]; }
        }
        int token = c * 256 + t;
        int row0 = off_l[e0] + base_l[e0] + woff0 + lp0;
        int row1 = off_l[e1] + base_l[e1] + woff1 + lp1;
        if ((row0 & 255) == bid) {
            int qi = atomicAdd(&qn, 1);
            qrow[qi] = row0; qtok[qi] = token; qw[qi] = top_w[token];
        }
        if ((row1 & 255) == bid) {
            int qi = atomicAdd(&qn, 1);
            qrow[qi] = row1; qtok[qi] = token; qw[qi] = top_w[NTOK + token];
        }
        __syncthreads();
        if (t < E_) base_l[t] += wcnt[t][0] + wcnt[t][1] + wcnt[t][2] + wcnt[t][3];
        __syncthreads();
    }

    // ---- gather owned rows: x (f32) -> Xg (bf16), plus inverse maps ----
    int nq = qn;
    for (int i = 0; i < nq; ++i) {
        int row = qrow[i]; int tok = qtok[i];
        float4 v = *(const float4*)(x + (size_t)tok * D_ + t * 4);
        uint2 uu;
        uu.x = pack2(v.x, v.y);
        uu.y = pack2(v.z, v.w);
        *(uint2*)(Xg + (size_t)row * D_ + t * 4) = uu;
        if (t == 0) { tok_row[row] = tok; w_row[row] = qw[i]; }
    }
}

// ---------------- weight transpose+convert, both weights in one launch ----------------
// [R][C] f32 -> [C][R] bf16 per expert, 64x64 tiles. First 8192 blocks: W1; rest: W2.
__global__ __launch_bounds__(256) void transpose_both_kernel(
    const float* __restrict__ W1, const float* __restrict__ W2,
    bf16* __restrict__ W1t, bf16* __restrict__ W2t)
{
    int bx = blockIdx.x;
    const float* in; bf16* outp; int R, C, idx;
    if (bx < E_ * 1024) { in = W1; outp = W1t; R = D_; C = F_; idx = bx; }
    else                { in = W2; outp = W2t; R = F_; C = D_; idx = bx - E_ * 1024; }
    int tilesR = R >> 6, tilesC = C >> 6;
    int per = tilesR * tilesC;
    int e  = idx / per; int r2 = idx % per;
    int tr = r2 / tilesC, tc = r2 % tilesC;
    int r0 = tr << 6, c0 = tc << 6;
    const float* ip = in  + (size_t)e * R * C;
    bf16*        op = outp + (size_t)e * R * C;

    __shared__ uint32_t T[64][36];   // [col][row-pair], padded stride
    int t = threadIdx.x;
    int rp = t >> 4;          // 0..15
    int c4 = (t & 15) * 4;

#pragma unroll
    for (int it = 0; it < 2; ++it) {
        int pr = rp + 16 * it;    // pair index 0..31
        const float* p = ip + (size_t)(r0 + 2*pr) * C + c0 + c4;
        float4 a = *(const float4*)(p);
        float4 b = *(const float4*)(p + C);
        T[c4+0][pr] = pack2(a.x, b.x);
        T[c4+1][pr] = pack2(a.y, b.y);
        T[c4+2][pr] = pack2(a.z, b.z);
        T[c4+3][pr] = pack2(a.w, b.w);
    }
    __syncthreads();

    int s     = t & 7;        // 16B segment within output row
    int cbase = t >> 3;       // 0..31
#pragma unroll
    for (int pass = 0; pass < 2; ++pass) {
        int cc = cbase + 32 * pass;
        uint4 u = *(const uint4*)&T[cc][4*s];
        *(uint4*)(op + (size_t)(c0 + cc) * R + r0 + 8*s) = u;
    }
}

// ============ GEMM1: H = gelu(Xg @ W1 + b1), bf16 out ============
// R0 form (known-good): 128x128 tile, 32 KiB LDS, 2-barrier loop, 2048 active blocks
// (8/CU available) -> cross-block wave overlap pipelines it (m97/m114 regime).
__global__ __launch_bounds__(256) void gemm1_kernel(
    const bf16* __restrict__ Xg, const bf16* __restrict__ W1t,
    const float* __restrict__ b1, const int* __restrict__ cnt,
    const int* __restrict__ off, bf16* __restrict__ H)
{
    int bx = blockIdx.x;
    int e  = bx >> 10;
    int r2 = bx & 1023;
    int mtile = r2 >> 5, ntile = r2 & 31;
    int n = cnt[e];
    if (mtile * 128 >= n) return;
    int row0 = off[e] + mtile * 128;
    int f0 = ntile * 128;

    __shared__ bf16 As[128*64];
    __shared__ bf16 Bs[128*64];

    int t = threadIdx.x;
    int wave = t >> 6, lane = t & 63;
    int wm = wave & 1, wn = wave >> 1;
    int q = lane >> 4, ln = lane & 15;
    int sm = lane >> 3, sc = lane & 7;

    const bf16* Abase = Xg  + (size_t)row0 * D_;
    const bf16* Bbase = W1t + ((size_t)e * F_ + f0) * D_;

    floatx4 acc[4][4];
#pragma unroll
    for (int mt = 0; mt < 4; ++mt)
#pragma unroll
        for (int nt = 0; nt < 4; ++nt) acc[mt][nt] = {0.f, 0.f, 0.f, 0.f};

    for (int kt = 0; kt < D_; kt += 64) {
        __syncthreads();
#pragma unroll
        for (int i = 0; i < 4; ++i) {
            int g = wave*4 + i;
            int m = g*8 + sm;
            int ca = sc ^ (m & 7);
            async_load16(Abase + (size_t)m * D_ + kt + ca*8, &As[g*512]);
            async_load16(Bbase + (size_t)m * D_ + kt + ca*8, &Bs[g*512]);
        }
        __syncthreads();
#pragma unroll
        for (int kk = 0; kk < 2; ++kk) {
            short8 av[4], bv[4];
#pragma unroll
            for (int mt = 0; mt < 4; ++mt) {
                int r = wm*64 + mt*16 + ln;
                int cs = (kk*4 + q) ^ (r & 7);
                av[mt] = *(const short8*)&As[r*64 + cs*8];
            }
#pragma unroll
            for (int nt = 0; nt < 4; ++nt) {
                int r = wn*64 + nt*16 + ln;
                int cs = (kk*4 + q) ^ (r & 7);
                bv[nt] = *(const short8*)&Bs[r*64 + cs*8];
            }
#pragma unroll
            for (int mt = 0; mt < 4; ++mt)
#pragma unroll
                for (int nt = 0; nt < 4; ++nt)
                    acc[mt][nt] = __builtin_amdgcn_mfma_f32_16x16x32_bf16(av[mt], bv[nt], acc[mt][nt], 0, 0, 0);
        }
    }

#pragma unroll
    for (int nt = 0; nt < 4; ++nt) {
        int f = f0 + wn*64 + nt*16 + ln;
        float b1v = b1[(size_t)e * F_ + f];
#pragma unroll
        for (int mt = 0; mt < 4; ++mt) {
            int rl = wm*64 + mt*16 + q*4;
#pragma unroll
            for (int r = 0; r < 4; ++r) {
                float v = acc[mt][nt][r] + b1v;
                H[(size_t)(row0 + rl + r) * F_ + f] = __float2bfloat16(fast_gelu(v));
            }
        }
    }
}

// ============ GEMM2 + combine fused: out[tok] += w * (H @ W2 + b2) ============
// v6: keeps v5's 128x64 tiles / 24 KiB LDS / XCD-chunked mapping (4+ blocks/CU,
// cross-block overlap regime). Epilogue scatters weighted f32 atomicAdd directly
// into out (pre-zeroed). Exactly 2 commutative adds per element -> deterministic.
// Removes combine kernel + Y buffer entirely.
__global__ __launch_bounds__(256) void gemm2_kernel(
    const bf16* __restrict__ H, const bf16* __restrict__ W2t,
    const float* __restrict__ b2, const int* __restrict__ cnt, const int* __restrict__ off,
    const int* __restrict__ mt_map, const int* __restrict__ mt_hdr,
    const int* __restrict__ tok_row, const float* __restrict__ w_row,
    float* __restrict__ out)
{
    int bx = blockIdx.x;
    int k  = bx & 7;          // XCD id under round-robin dispatch
    int j  = bx >> 3;         // position within XCD: 0..143
    int jj = j >> 4;          // chunk-local mtile index
    int ntile = j & 15;       // 16 ntiles of 64 cols
    int nmt = mt_hdr[0], qc = mt_hdr[1];
    if (jj >= qc) return;
    int mt = k * qc + jj;     // contiguous mtile chunk per XCD
    if (mt >= nmt) return;
    int em = mt_map[mt];
    int e = em >> 8, mtile = em & 255;
    int n = cnt[e];
    int row0 = off[e] + mtile * 128;
    int d0 = ntile * 64;

    __shared__ bf16 As[128*64];   // 16 KiB
    __shared__ bf16 Bs[64*64];    // 8 KiB

    int t = threadIdx.x;
    int wave = t >> 6, lane = t & 63;
    int wm = wave & 1, wn = wave >> 1;     // 2 (m) x 2 (n) wave grid
    int q = lane >> 4, ln = lane & 15;
    int sm = lane >> 3, sc = lane & 7;

    const bf16* Abase = H   + (size_t)row0 * F_;
    const bf16* Bbase = W2t + ((size_t)e * D_ + d0) * F_;

    floatx4 acc[4][2];
#pragma unroll
    for (int mt2 = 0; mt2 < 4; ++mt2)
#pragma unroll
        for (int nt = 0; nt < 2; ++nt) acc[mt2][nt] = {0.f, 0.f, 0.f, 0.f};

    for (int kt = 0; kt < F_; kt += 64) {
        __syncthreads();
#pragma unroll
        for (int i = 0; i < 4; ++i) {
            int g = wave*4 + i;
            int m = g*8 + sm;
            int ca = sc ^ (m & 7);
            async_load16(Abase + (size_t)m * F_ + kt + ca*8, &As[g*512]);
        }
#pragma unroll
        for (int i = 0; i < 2; ++i) {
            int g = wave*2 + i;
            int m = g*8 + sm;
            int ca = sc ^ (m & 7);
            async_load16(Bbase + (size_t)m * F_ + kt + ca*8, &Bs[g*512]);
        }
        __syncthreads();
#pragma unroll
        for (int kk = 0; kk < 2; ++kk) {
            short8 av[4], bv[2];
#pragma unroll
            for (int mt2 = 0; mt2 < 4; ++mt2) {
                int r = wm*64 + mt2*16 + ln;
                int cs = (kk*4 + q) ^ (r & 7);
                av[mt2] = *(const short8*)&As[r*64 + cs*8];
            }
#pragma unroll
            for (int nt = 0; nt < 2; ++nt) {
                int r = wn*32 + nt*16 + ln;
                int cs = (kk*4 + q) ^ (r & 7);
                bv[nt] = *(const short8*)&Bs[r*64 + cs*8];
            }
#pragma unroll
            for (int mt2 = 0; mt2 < 4; ++mt2)
#pragma unroll
                for (int nt = 0; nt < 2; ++nt)
                    acc[mt2][nt] = __builtin_amdgcn_mfma_f32_16x16x32_bf16(av[mt2], bv[nt], acc[mt2][nt], 0, 0, 0);
        }
    }

    float b2v[2];
#pragma unroll
    for (int nt = 0; nt < 2; ++nt)
        b2v[nt] = b2[(size_t)e * D_ + d0 + wn*32 + nt*16 + ln];

#pragma unroll
    for (int mt2 = 0; mt2 < 4; ++mt2) {
#pragma unroll
        for (int r = 0; r < 4; ++r) {
            int loc = wm*64 + mt2*16 + q*4 + r;
            int i = mtile*128 + loc;
            if (i < n) {
                int tok = tok_row[row0 + loc];
                float w = w_row[row0 + loc];
                float* op = out + (size_t)tok * D_ + d0 + wn*32 + ln;
#pragma unroll
                for (int nt = 0; nt < 2; ++nt)
                    atomicAdd(op + nt*16, w * (acc[mt2][nt][r] + b2v[nt]));
            }
        }
    }
}

extern "C" void kernel_launch(void* const* d_in, const int* in_sizes, int n_in,
                              void* d_out, int out_size, void* d_ws, size_t ws_size,
                              hipStream_t stream)
{
    const float* x  = (const float*)d_in[0];
    const float* Wg = (const float*)d_in[1];
    const float* bg = (const float*)d_in[2];
    const float* W1 = (const float*)d_in[3];
    const float* b1 = (const float*)d_in[4];
    const float* W2 = (const float*)d_in[5];
    const float* b2 = (const float*)d_in[6];
    float* out = (float*)d_out;

    char* ws = (char*)d_ws;
    int*      cnt      = (int*)(ws + 0);
    int*      off      = (int*)(ws + 128);
    int*      mt_map   = (int*)(ws + 256);               // 72 ints
    int*      mt_hdr   = (int*)(ws + 576);               // 2 ints
    float*    psum_pad = (float*)(ws + 1024);
    uint32_t* top_ids  = (uint32_t*)(ws + 8192);
    float*    top_w    = (float*)(ws + 8192 + 16384);
    int*      tok_row  = (int*)(ws + 65536);             // [MAXROWS]
    float*    w_row    = (float*)(ws + 65536 + 65536);   // [MAXROWS]
    size_t o = 1u << 20;
    bf16*  W1t = (bf16*)(ws + o);  o += (size_t)E_ * D_ * F_ * 2;   // 64 MB
    bf16*  W2t = (bf16*)(ws + o);  o += (size_t)E_ * F_ * D_ * 2;   // 64 MB
    bf16*  Xg  = (bf16*)(ws + o);  o += (size_t)MAXROWS * D_ * 2;   // 18.9 MB
    bf16*  H   = (bf16*)(ws + o);                                    // 75.5 MB

    hipMemsetAsync(ws + 1024, 0, 1024, stream);                      // psum_pad
    hipMemsetAsync(out, 0, (size_t)NTOK * D_ * sizeof(float), stream); // accum target

    transpose_both_kernel<<<E_ * 1024 * 2, 256, 0, stream>>>(W1, W2, W1t, W2t);

    gate_kernel<<<256, 256, 0, stream>>>(x, Wg, bg, psum_pad, top_ids, top_w);
    dispatch_kernel<<<256, 256, 0, stream>>>(x, top_ids, top_w, psum_pad,
                                             cnt, off, mt_map, mt_hdr,
                                             tok_row, w_row, Xg,
                                             out + (size_t)NTOK * D_);

    gemm1_kernel<<<E_ * 32 * 32, 256, 0, stream>>>(Xg, W1t, b1, cnt, off, H);
    gemm2_kernel<<<MAXMT * 16, 256, 0, stream>>>(H, W2t, b2, cnt, off, mt_map, mt_hdr,
                                                 tok_row, w_row, out);
}